// Round 8
// baseline (848.164 us; speedup 1.0000x reference)
//
#include <hip/hip_runtime.h>
#include <hip/hip_bf16.h>

#define NTOK 1024
#define HDIM 2880
#define IDIM 2880
#define NEXP 8
#define BK 64
#define NT 45  // HDIM/BK

typedef __attribute__((ext_vector_type(4))) float fx4;
typedef __attribute__((ext_vector_type(8))) short sx8;
typedef __attribute__((ext_vector_type(8))) unsigned short usx8;

typedef const __attribute__((address_space(1))) void* gas_p;
typedef __attribute__((address_space(3))) void* las_p;

__device__ __forceinline__ unsigned short f2bf(float f) {
  __hip_bfloat16 b = __float2bfloat16(f);
  return __builtin_bit_cast(unsigned short, b);
}
__device__ __forceinline__ usx8 cvt8(fx4 a, fx4 b) {
  usx8 u = {f2bf(a.x), f2bf(a.y), f2bf(a.z), f2bf(a.w),
            f2bf(b.x), f2bf(b.y), f2bf(b.z), f2bf(b.w)};
  return u;
}

#define MFMA16(a, b, c) __builtin_amdgcn_mfma_f32_16x16x32_bf16(a, b, c, 0, 0, 0)

__global__ __launch_bounds__(256) void init_out_k(const float* __restrict__ x,
                                                  float* __restrict__ out) {
  int i = blockIdx.x * 256 + threadIdx.x;
  ((fx4*)out)[i] = ((const fx4*)x)[i];
}

__global__ __launch_bounds__(256) void rms_router_k(
    const float* __restrict__ x, const float* __restrict__ norm_w,
    const float* __restrict__ gate_w, const float* __restrict__ gate_b,
    unsigned short* __restrict__ t_bf, int* __restrict__ cnt,
    int* __restrict__ tok, float* __restrict__ wgt) {
  const int n = blockIdx.x;
  const int tid = threadIdx.x;
  const int wid = tid >> 6, lane = tid & 63;
  const float* xr = x + (size_t)n * HDIM;

  float ss = 0.f;
  for (int h = tid; h < HDIM; h += 256) { float v = xr[h]; ss += v * v; }
  #pragma unroll
  for (int o = 32; o > 0; o >>= 1) ss += __shfl_down(ss, o);
  __shared__ float sred[4];
  if (lane == 0) sred[wid] = ss;
  __syncthreads();
  const float rstd =
      rsqrtf((sred[0] + sred[1] + sred[2] + sred[3]) * (1.0f / HDIM) + 1e-5f);

  float p[NEXP];
  #pragma unroll
  for (int e = 0; e < NEXP; e++) p[e] = 0.f;
  for (int h = tid; h < HDIM; h += 256) {
    float xv = xr[h] * norm_w[h];
    t_bf[(size_t)n * HDIM + h] = f2bf(xv * rstd);
    #pragma unroll
    for (int e = 0; e < NEXP; e++) p[e] += xv * gate_w[e * HDIM + h];
  }
  __shared__ float pls[4][NEXP];
  #pragma unroll
  for (int e = 0; e < NEXP; e++) {
    float v = p[e];
    #pragma unroll
    for (int o = 32; o > 0; o >>= 1) v += __shfl_down(v, o);
    if (lane == 0) pls[wid][e] = v;
  }
  __syncthreads();
  if (tid == 0) {
    float lg[NEXP];
    #pragma unroll
    for (int e = 0; e < NEXP; e++)
      lg[e] = (pls[0][e] + pls[1][e] + pls[2][e] + pls[3][e]) * rstd + gate_b[e];
    unsigned used = 0;
    float val[4];
    int idx[4];
    for (int k = 0; k < 4; k++) {
      float best = -1e30f;
      int bi = 0;
      for (int e = 0; e < NEXP; e++)
        if (!((used >> e) & 1u) && lg[e] > best) { best = lg[e]; bi = e; }
      used |= 1u << bi;
      val[k] = best;
      idx[k] = bi;
    }
    float sum = 0.f, w[4];
    for (int k = 0; k < 4; k++) { w[k] = expf(val[k] - val[0]); sum += w[k]; }
    for (int k = 0; k < 4; k++) {
      int e = idx[k];
      int slot = atomicAdd(&cnt[e], 1);
      tok[e * NTOK + slot] = n;
      wgt[e * NTOK + slot] = w[k] / sum;
    }
  }
}

// GEMM1 (m97-structure): 128 rows x (64 G + 64 L), BK=64, 4 waves (2x2),
// single-buffer LDS 32 KB, 3 blocks/CU. barrier-STAGE-barrier-COMPUTE.
__global__ __launch_bounds__(256, 3) void gemm1_k(
    const unsigned short* __restrict__ t_bf,
    const float* __restrict__ w_gate_up, const float* __restrict__ b_gate_up,
    const int* __restrict__ cnt, const int* __restrict__ tok,
    unsigned short* __restrict__ act_bf) {
  const int h = blockIdx.x;
  const int z = h / 360;          // row-tile
  const int u = h % 360;          // (expert, col-slice); twins share u -> XCD
  const int e = u / 45;
  const int c0 = (u % 45) * 64;
  const int m0 = z * 128;
  const int ce = cnt[e];
  if (m0 >= ce) return;

  const int tid = threadIdx.x, lane = tid & 63, wid = tid >> 6;
  const int fr = lane & 15, fq = lane >> 4;
  const int wm = wid >> 1, wn = wid & 1;

  __shared__ __align__(16) unsigned short Ash[128 * 64];  // 16 KB
  __shared__ __align__(16) unsigned short Bsh[128 * 64];  // 16 KB (G:0-63,L:64-127)

  const fx4 FZ = {0.f, 0.f, 0.f, 0.f};
  fx4 accG[4][2], accL[4][2];
  #pragma unroll
  for (int m = 0; m < 4; m++)
    #pragma unroll
    for (int n = 0; n < 2; n++) { accG[m][n] = FZ; accL[m][n] = FZ; }

  // A: 4 gload_lds per thread; instr j covers rows [wid*32+j*8, +8).
  // Source chunk pre-swizzled (r5/r6-verified conflict-free).
  const unsigned short* gA[4];
  #pragma unroll
  for (int j = 0; j < 4; ++j) {
    int R = m0 + wid * 32 + j * 8 + (lane >> 3);
    int rc = R < ce ? R : ce - 1;
    gA[j] = t_bf + (size_t)tok[e * NTOK + rc] * HDIM +
            ((lane & 7) ^ ((lane >> 3) & 7)) * 8;
  }
  // B: 128 rows (64 G + 64 L) x 64 floats; thread: row tid>>1,
  // chunks [(tid&1)*4, +4) (8 floats each).
  const int bRow = tid >> 1, bC0 = (tid & 1) * 4;
  const int wrow = bRow < 64 ? (c0 + bRow) : (IDIM + c0 + (bRow - 64));
  const float* srcB = w_gate_up + (size_t)e * (2 * IDIM) * HDIM +
                      (size_t)wrow * HDIM + bC0 * 8;
  const int bSw = bRow & 7;

  for (int t = 0; t < NT; ++t) {
    const int ko = t * BK;
    __syncthreads();  // all waves done reading previous tile
    #pragma unroll
    for (int j = 0; j < 4; ++j)
      __builtin_amdgcn_global_load_lds((gas_p)(gA[j] + ko),
                                       (las_p)&Ash[(wid * 32 + j * 8) * 64], 16,
                                       0, 0);
    {
      fx4 v[8];
      #pragma unroll
      for (int q = 0; q < 8; ++q) v[q] = *(const fx4*)(srcB + ko + q * 4);
      #pragma unroll
      for (int q = 0; q < 4; ++q)
        *(usx8*)&Bsh[bRow * 64 + (((bC0 + q) ^ bSw) * 8)] =
            cvt8(v[2 * q], v[2 * q + 1]);
    }
    __syncthreads();  // stage visible (compiler drains vmcnt/lgkm here)
    #pragma unroll
    for (int ks = 0; ks < 2; ++ks) {
      const int rc = (ks * 4 + fq);
      sx8 aF[4], bG[2], bL[2];
      #pragma unroll
      for (int m = 0; m < 4; ++m)
        aF[m] = *(const sx8*)&Ash[(wm * 64 + m * 16 + fr) * 64 +
                                  ((rc ^ (fr & 7)) * 8)];
      #pragma unroll
      for (int n = 0; n < 2; ++n) {
        bG[n] = *(const sx8*)&Bsh[(wn * 32 + n * 16 + fr) * 64 +
                                  ((rc ^ (fr & 7)) * 8)];
        bL[n] = *(const sx8*)&Bsh[(64 + wn * 32 + n * 16 + fr) * 64 +
                                  ((rc ^ (fr & 7)) * 8)];
      }
      __builtin_amdgcn_s_setprio(1);
      #pragma unroll
      for (int n = 0; n < 2; ++n)
        #pragma unroll
        for (int m = 0; m < 4; ++m) {
          accG[m][n] = MFMA16(aF[m], bG[n], accG[m][n]);
          accL[m][n] = MFMA16(aF[m], bL[n], accL[m][n]);
        }
      __builtin_amdgcn_s_setprio(0);
    }
  }

  #pragma unroll
  for (int n = 0; n < 2; ++n) {
    const int col = c0 + wn * 32 + n * 16 + fr;
    const float bg = b_gate_up[e * (2 * IDIM) + col];
    const float bl = b_gate_up[e * (2 * IDIM) + IDIM + col];
    #pragma unroll
    for (int m = 0; m < 4; ++m) {
      #pragma unroll
      for (int r = 0; r < 4; ++r) {
        int slot = m0 + wm * 64 + m * 16 + fq * 4 + r;
        if (slot < ce) {
          float g = accG[m][n][r] + bg;
          float l = accL[m][n][r] + bl;
          float a = g * (1.0f / (1.0f + __expf(-1.702f * g))) * (l + 1.0f);
          act_bf[((size_t)e * NTOK + slot) * IDIM + col] = f2bf(a);
        }
      }
    }
  }
}

// GEMM2 (m97-structure): 128 rows x 96 cols, BK=64, 4 waves (2x2),
// single-buffer LDS 28 KB, 3 blocks/CU.
__global__ __launch_bounds__(256, 3) void gemm2_k(
    const unsigned short* __restrict__ act_bf, const float* __restrict__ w_down,
    const float* __restrict__ b_down, const int* __restrict__ cnt,
    const int* __restrict__ tok, const float* __restrict__ wgt,
    float* __restrict__ out) {
  const int h = blockIdx.x;
  const int z = h / 240;
  const int u = h % 240;
  const int e = u / 30;
  const int c0 = (u % 30) * 96;
  const int m0 = z * 128;
  const int ce = cnt[e];
  if (m0 >= ce) return;

  const int tid = threadIdx.x, lane = tid & 63, wid = tid >> 6;
  const int fr = lane & 15, fq = lane >> 4;
  const int wm = wid >> 1, wn = wid & 1;

  __shared__ __align__(16) unsigned short Ash[128 * 64];  // 16 KB
  __shared__ __align__(16) unsigned short Bsh[96 * 64];   // 12 KB

  const fx4 FZ = {0.f, 0.f, 0.f, 0.f};
  fx4 acc[4][3];
  #pragma unroll
  for (int m = 0; m < 4; m++)
    #pragma unroll
    for (int n = 0; n < 3; n++) acc[m][n] = FZ;

  const unsigned short* gA[4];
  #pragma unroll
  for (int j = 0; j < 4; ++j) {
    int R = m0 + wid * 32 + j * 8 + (lane >> 3);
    int rc = R < ce ? R : ce - 1;
    gA[j] = act_bf + ((size_t)e * NTOK + rc) * IDIM +
            ((lane & 7) ^ ((lane >> 3) & 7)) * 8;
  }
  // B: 96 rows x 8 chunks = 768 chunk-slots; thread covers f = tid + 256q.
  const float* wb = w_down + (size_t)e * HDIM * IDIM;
  const float* srcB[3];
  int bR[3], bC[3];
  #pragma unroll
  for (int q = 0; q < 3; ++q) {
    int f = tid + 256 * q;
    bR[q] = f >> 3;
    bC[q] = f & 7;
    srcB[q] = wb + (size_t)(c0 + bR[q]) * IDIM + bC[q] * 8;
  }

  for (int t = 0; t < NT; ++t) {
    const int ko = t * BK;
    __syncthreads();
    #pragma unroll
    for (int j = 0; j < 4; ++j)
      __builtin_amdgcn_global_load_lds((gas_p)(gA[j] + ko),
                                       (las_p)&Ash[(wid * 32 + j * 8) * 64], 16,
                                       0, 0);
    {
      fx4 v[6];
      #pragma unroll
      for (int q = 0; q < 3; ++q) {
        v[2 * q] = *(const fx4*)(srcB[q] + ko);
        v[2 * q + 1] = *(const fx4*)(srcB[q] + ko + 4);
      }
      #pragma unroll
      for (int q = 0; q < 3; ++q)
        *(usx8*)&Bsh[bR[q] * 64 + ((bC[q] ^ (bR[q] & 7)) * 8)] =
            cvt8(v[2 * q], v[2 * q + 1]);
    }
    __syncthreads();
    #pragma unroll
    for (int ks = 0; ks < 2; ++ks) {
      const int rc = (ks * 4 + fq);
      sx8 aF[4], bB[3];
      #pragma unroll
      for (int m = 0; m < 4; ++m)
        aF[m] = *(const sx8*)&Ash[(wm * 64 + m * 16 + fr) * 64 +
                                  ((rc ^ (fr & 7)) * 8)];
      #pragma unroll
      for (int n = 0; n < 3; ++n)
        bB[n] = *(const sx8*)&Bsh[(wn * 48 + n * 16 + fr) * 64 +
                                  ((rc ^ (fr & 7)) * 8)];
      __builtin_amdgcn_s_setprio(1);
      #pragma unroll
      for (int n = 0; n < 3; ++n)
        #pragma unroll
        for (int m = 0; m < 4; ++m)
          acc[m][n] = MFMA16(aF[m], bB[n], acc[m][n]);
      __builtin_amdgcn_s_setprio(0);
    }
  }

  #pragma unroll
  for (int n = 0; n < 3; ++n) {
    const int col = c0 + wn * 48 + n * 16 + fr;
    const float bias = b_down[e * HDIM + col];
    #pragma unroll
    for (int m = 0; m < 4; ++m) {
      #pragma unroll
      for (int r = 0; r < 4; ++r) {
        int slot = m0 + wm * 64 + m * 16 + fq * 4 + r;
        if (slot < ce) {
          int token = tok[e * NTOK + slot];
          float w = wgt[e * NTOK + slot];
          atomicAdd(&out[(size_t)token * HDIM + col], w * (acc[m][n][r] + bias));
        }
      }
    }
  }
}

extern "C" void kernel_launch(void* const* d_in, const int* in_sizes, int n_in,
                              void* d_out, int out_size, void* d_ws,
                              size_t ws_size, hipStream_t stream) {
  const float* x = (const float*)d_in[0];
  const float* norm_w = (const float*)d_in[1];
  const float* gate_w = (const float*)d_in[2];
  const float* gate_b = (const float*)d_in[3];
  const float* w_gate_up = (const float*)d_in[4];
  const float* b_gate_up = (const float*)d_in[5];
  const float* w_down = (const float*)d_in[6];
  const float* b_down = (const float*)d_in[7];
  float* out = (float*)d_out;

  char* ws = (char*)d_ws;
  unsigned short* t_bf = (unsigned short*)ws;
  ws += (size_t)NTOK * HDIM * 2;
  unsigned short* act_bf = (unsigned short*)ws;
  ws += (size_t)NEXP * NTOK * IDIM * 2;
  int* cnt = (int*)ws;
  ws += 256;
  int* tok = (int*)ws;
  ws += (size_t)NEXP * NTOK * 4;
  float* wgt = (float*)ws;
  ws += (size_t)NEXP * NTOK * 4;

  hipMemsetAsync(cnt, 0, NEXP * sizeof(int), stream);
  init_out_k<<<2880, 256, 0, stream>>>(x, out);
  rms_router_k<<<NTOK, 256, 0, stream>>>(x, norm_w, gate_w, gate_b, t_bf, cnt,
                                         tok, wgt);
  // h = z*NU + u : row-tile twins (same u) stride NU % 8 == 0 -> same XCD,
  // co-resident within ~3 generations -> weight re-reads are L2 hits.
  gemm1_k<<<8 * 360, 256, 0, stream>>>(t_bf, w_gate_up, b_gate_up, cnt, tok,
                                       act_bf);
  gemm2_k<<<8 * 240, 256, 0, stream>>>(act_bf, w_down, b_down, cnt, tok, wgt,
                                       out);
}

// Round 9
// 654.299 us; speedup vs baseline: 1.2963x; 1.2963x over previous
//
#include <hip/hip_runtime.h>
#include <hip/hip_bf16.h>

#define NTOK 1024
#define HDIM 2880
#define IDIM 2880
#define NEXP 8
#define BK 64
#define NT 45  // HDIM/BK

typedef __attribute__((ext_vector_type(4))) float fx4;
typedef __attribute__((ext_vector_type(8))) short sx8;
typedef __attribute__((ext_vector_type(8))) unsigned short usx8;

typedef const __attribute__((address_space(1))) void* gas_p;
typedef __attribute__((address_space(3))) void* las_p;

__device__ __forceinline__ unsigned short f2bf(float f) {
  __hip_bfloat16 b = __float2bfloat16(f);
  return __builtin_bit_cast(unsigned short, b);
}
__device__ __forceinline__ usx8 cvt8(fx4 a, fx4 b) {
  usx8 u = {f2bf(a.x), f2bf(a.y), f2bf(a.z), f2bf(a.w),
            f2bf(b.x), f2bf(b.y), f2bf(b.z), f2bf(b.w)};
  return u;
}

#define MFMA16(a, b, c) __builtin_amdgcn_mfma_f32_16x16x32_bf16(a, b, c, 0, 0, 0)

__global__ __launch_bounds__(256) void init_out_k(const float* __restrict__ x,
                                                  float* __restrict__ out) {
  int i = blockIdx.x * 256 + threadIdx.x;
  ((fx4*)out)[i] = ((const fx4*)x)[i];
}

__global__ __launch_bounds__(256) void rms_router_k(
    const float* __restrict__ x, const float* __restrict__ norm_w,
    const float* __restrict__ gate_w, const float* __restrict__ gate_b,
    unsigned short* __restrict__ t_bf, int* __restrict__ cnt,
    int* __restrict__ tok, float* __restrict__ wgt) {
  const int n = blockIdx.x;
  const int tid = threadIdx.x;
  const int wid = tid >> 6, lane = tid & 63;
  const float* xr = x + (size_t)n * HDIM;

  float ss = 0.f;
  for (int h = tid; h < HDIM; h += 256) { float v = xr[h]; ss += v * v; }
  #pragma unroll
  for (int o = 32; o > 0; o >>= 1) ss += __shfl_down(ss, o);
  __shared__ float sred[4];
  if (lane == 0) sred[wid] = ss;
  __syncthreads();
  const float rstd =
      rsqrtf((sred[0] + sred[1] + sred[2] + sred[3]) * (1.0f / HDIM) + 1e-5f);

  float p[NEXP];
  #pragma unroll
  for (int e = 0; e < NEXP; e++) p[e] = 0.f;
  for (int h = tid; h < HDIM; h += 256) {
    float xv = xr[h] * norm_w[h];
    t_bf[(size_t)n * HDIM + h] = f2bf(xv * rstd);
    #pragma unroll
    for (int e = 0; e < NEXP; e++) p[e] += xv * gate_w[e * HDIM + h];
  }
  __shared__ float pls[4][NEXP];
  #pragma unroll
  for (int e = 0; e < NEXP; e++) {
    float v = p[e];
    #pragma unroll
    for (int o = 32; o > 0; o >>= 1) v += __shfl_down(v, o);
    if (lane == 0) pls[wid][e] = v;
  }
  __syncthreads();
  if (tid == 0) {
    float lg[NEXP];
    #pragma unroll
    for (int e = 0; e < NEXP; e++)
      lg[e] = (pls[0][e] + pls[1][e] + pls[2][e] + pls[3][e]) * rstd + gate_b[e];
    unsigned used = 0;
    float val[4];
    int idx[4];
    for (int k = 0; k < 4; k++) {
      float best = -1e30f;
      int bi = 0;
      for (int e = 0; e < NEXP; e++)
        if (!((used >> e) & 1u) && lg[e] > best) { best = lg[e]; bi = e; }
      used |= 1u << bi;
      val[k] = best;
      idx[k] = bi;
    }
    float sum = 0.f, w[4];
    for (int k = 0; k < 4; k++) { w[k] = expf(val[k] - val[0]); sum += w[k]; }
    for (int k = 0; k < 4; k++) {
      int e = idx[k];
      int slot = atomicAdd(&cnt[e], 1);
      tok[e * NTOK + slot] = n;
      wgt[e * NTOK + slot] = w[k] / sum;
    }
  }
}

// GEMM1: BM=256 x (64 G + 64 L), BK=64, 8 waves (4m x 2n), single-buf 48 KB,
// 2 blocks/CU. Twin-adjacent grid (h = u*4+z). B reg-prefetch under compute.
__global__ __launch_bounds__(512, 4) void gemm1_k(
    const unsigned short* __restrict__ t_bf,
    const float* __restrict__ w_gate_up, const float* __restrict__ b_gate_up,
    const int* __restrict__ cnt, const int* __restrict__ tok,
    unsigned short* __restrict__ act_bf) {
  const int h = blockIdx.x;
  const int u = h >> 2, z = h & 3;  // twins adjacent
  const int e = u / 45;
  const int c0 = (u % 45) * 64;
  const int m0 = z * 256;
  const int ce = cnt[e];
  if (m0 >= ce) return;

  const int tid = threadIdx.x, lane = tid & 63, wid = tid >> 6;
  const int fr = lane & 15, fq = lane >> 4;
  const int wm = wid >> 1, wn = wid & 1;

  __shared__ __align__(16) unsigned short Ash[256 * 64];  // 32 KB
  __shared__ __align__(16) unsigned short Bsh[128 * 64];  // 16 KB (G:0-63 L:64-127)

  const fx4 FZ = {0.f, 0.f, 0.f, 0.f};
  fx4 accG[4][2], accL[4][2];
  #pragma unroll
  for (int m = 0; m < 4; m++)
    #pragma unroll
    for (int n = 0; n < 2; n++) { accG[m][n] = FZ; accL[m][n] = FZ; }

  // A: wave stages rows [wid*32, +32) via 4 gload_lds (8 rows each);
  // source chunk pre-swizzled (verified conflict-free r5/r6/r8).
  const unsigned short* gA[4];
  #pragma unroll
  for (int j = 0; j < 4; ++j) {
    int R = m0 + wid * 32 + j * 8 + (lane >> 3);
    int rc = R < ce ? R : ce - 1;
    gA[j] = t_bf + (size_t)tok[e * NTOK + rc] * HDIM +
            ((lane & 7) ^ ((lane >> 3) & 7)) * 8;
  }
  // B: thread covers G row (tid>>3) chunk (tid&7) and the matching L row.
  const int bR = tid >> 3, bC = tid & 7;
  const float* srcG = w_gate_up + (size_t)e * (2 * IDIM) * HDIM +
                      (size_t)(c0 + bR) * HDIM + bC * 8;
  const float* srcL = srcG + (size_t)IDIM * HDIM;
  const int bsw = (bC ^ (bR & 7)) * 8;  // 64 % 8 == 0 -> same slot for L row

  fx4 rG0, rG1, rL0, rL1;
  rG0 = *(const fx4*)(srcG);
  rG1 = *(const fx4*)(srcG + 4);
  rL0 = *(const fx4*)(srcL);
  rL1 = *(const fx4*)(srcL + 4);

  for (int t = 0; t < NT; ++t) {
    const int ko = t * BK;
    __syncthreads();  // all waves done reading previous tile
    #pragma unroll
    for (int j = 0; j < 4; ++j)
      __builtin_amdgcn_global_load_lds((gas_p)(gA[j] + ko),
                                       (las_p)&Ash[(wid * 32 + j * 8) * 64], 16,
                                       0, 0);
    *(usx8*)&Bsh[bR * 64 + bsw] = cvt8(rG0, rG1);
    *(usx8*)&Bsh[(64 + bR) * 64 + bsw] = cvt8(rL0, rL1);
    __syncthreads();  // tile visible (drains A DMA + B writes)
    // prefetch B(t+1) -> regs; lands while we compute tile t
    const int kf = (t + 1 < NT ? (t + 1) * BK : 0);
    rG0 = *(const fx4*)(srcG + kf);
    rG1 = *(const fx4*)(srcG + kf + 4);
    rL0 = *(const fx4*)(srcL + kf);
    rL1 = *(const fx4*)(srcL + kf + 4);
    #pragma unroll
    for (int ks = 0; ks < 2; ++ks) {
      const int rc = ks * 4 + fq;
      sx8 aF[4], bG[2], bL[2];
      #pragma unroll
      for (int m = 0; m < 4; ++m)
        aF[m] = *(const sx8*)&Ash[(wm * 64 + m * 16 + fr) * 64 +
                                  ((rc ^ (fr & 7)) * 8)];
      #pragma unroll
      for (int n = 0; n < 2; ++n) {
        bG[n] = *(const sx8*)&Bsh[(wn * 32 + n * 16 + fr) * 64 +
                                  ((rc ^ (fr & 7)) * 8)];
        bL[n] = *(const sx8*)&Bsh[(64 + wn * 32 + n * 16 + fr) * 64 +
                                  ((rc ^ (fr & 7)) * 8)];
      }
      __builtin_amdgcn_s_setprio(1);
      #pragma unroll
      for (int n = 0; n < 2; ++n)
        #pragma unroll
        for (int m = 0; m < 4; ++m) {
          accG[m][n] = MFMA16(aF[m], bG[n], accG[m][n]);
          accL[m][n] = MFMA16(aF[m], bL[n], accL[m][n]);
        }
      __builtin_amdgcn_s_setprio(0);
    }
  }

  #pragma unroll
  for (int n = 0; n < 2; ++n) {
    const int col = c0 + wn * 32 + n * 16 + fr;
    const float bg = b_gate_up[e * (2 * IDIM) + col];
    const float bl = b_gate_up[e * (2 * IDIM) + IDIM + col];
    #pragma unroll
    for (int m = 0; m < 4; ++m) {
      #pragma unroll
      for (int r = 0; r < 4; ++r) {
        int slot = m0 + wm * 64 + m * 16 + fq * 4 + r;
        if (slot < ce) {
          float g = accG[m][n][r] + bg;
          float l = accL[m][n][r] + bl;
          float a = g * (1.0f / (1.0f + __expf(-1.702f * g))) * (l + 1.0f);
          act_bf[((size_t)e * NTOK + slot) * IDIM + col] = f2bf(a);
        }
      }
    }
  }
}

// GEMM2: BM=256 x 96 cols, BK=64, 8 waves (4m x 2n), single-buf 44 KB,
// 2 blocks/CU. Twin-adjacent grid.
__global__ __launch_bounds__(512, 4) void gemm2_k(
    const unsigned short* __restrict__ act_bf, const float* __restrict__ w_down,
    const float* __restrict__ b_down, const int* __restrict__ cnt,
    const int* __restrict__ tok, const float* __restrict__ wgt,
    float* __restrict__ out) {
  const int h = blockIdx.x;
  const int u = h >> 2, z = h & 3;
  const int e = u / 30;
  const int c0 = (u % 30) * 96;
  const int m0 = z * 256;
  const int ce = cnt[e];
  if (m0 >= ce) return;

  const int tid = threadIdx.x, lane = tid & 63, wid = tid >> 6;
  const int fr = lane & 15, fq = lane >> 4;
  const int wm = wid >> 1, wn = wid & 1;

  __shared__ __align__(16) unsigned short Ash[256 * 64];  // 32 KB
  __shared__ __align__(16) unsigned short Bsh[96 * 64];   // 12 KB

  const fx4 FZ = {0.f, 0.f, 0.f, 0.f};
  fx4 acc[4][3];
  #pragma unroll
  for (int m = 0; m < 4; m++)
    #pragma unroll
    for (int n = 0; n < 3; n++) acc[m][n] = FZ;

  const unsigned short* gA[4];
  #pragma unroll
  for (int j = 0; j < 4; ++j) {
    int R = m0 + wid * 32 + j * 8 + (lane >> 3);
    int rc = R < ce ? R : ce - 1;
    gA[j] = act_bf + ((size_t)e * NTOK + rc) * IDIM +
            ((lane & 7) ^ ((lane >> 3) & 7)) * 8;
  }
  // B: 96 rows x 8 chunks = 768 slots; thread covers slot tid, and
  // (tid<256) slot 512+tid.
  const int bR0 = tid >> 3, bC0 = tid & 7;
  const float* wb = w_down + (size_t)e * HDIM * IDIM;
  const float* srcB0 = wb + (size_t)(c0 + bR0) * IDIM + bC0 * 8;
  const float* srcB1 = wb + (size_t)(c0 + 64 + bR0) * IDIM + bC0 * 8;
  const int bsw0 = (bC0 ^ (bR0 & 7)) * 8;

  fx4 r0a, r0b, r1a, r1b;
  r0a = *(const fx4*)(srcB0);
  r0b = *(const fx4*)(srcB0 + 4);
  if (tid < 256) {
    r1a = *(const fx4*)(srcB1);
    r1b = *(const fx4*)(srcB1 + 4);
  }

  for (int t = 0; t < NT; ++t) {
    const int ko = t * BK;
    __syncthreads();
    #pragma unroll
    for (int j = 0; j < 4; ++j)
      __builtin_amdgcn_global_load_lds((gas_p)(gA[j] + ko),
                                       (las_p)&Ash[(wid * 32 + j * 8) * 64], 16,
                                       0, 0);
    *(usx8*)&Bsh[bR0 * 64 + bsw0] = cvt8(r0a, r0b);
    if (tid < 256) *(usx8*)&Bsh[(64 + bR0) * 64 + bsw0] = cvt8(r1a, r1b);
    __syncthreads();
    const int kf = (t + 1 < NT ? (t + 1) * BK : 0);
    r0a = *(const fx4*)(srcB0 + kf);
    r0b = *(const fx4*)(srcB0 + kf + 4);
    if (tid < 256) {
      r1a = *(const fx4*)(srcB1 + kf);
      r1b = *(const fx4*)(srcB1 + kf + 4);
    }
    #pragma unroll
    for (int ks = 0; ks < 2; ++ks) {
      const int rc = ks * 4 + fq;
      sx8 aF[4], bB[3];
      #pragma unroll
      for (int m = 0; m < 4; ++m)
        aF[m] = *(const sx8*)&Ash[(wm * 64 + m * 16 + fr) * 64 +
                                  ((rc ^ (fr & 7)) * 8)];
      #pragma unroll
      for (int n = 0; n < 3; ++n)
        bB[n] = *(const sx8*)&Bsh[(wn * 48 + n * 16 + fr) * 64 +
                                  ((rc ^ (fr & 7)) * 8)];
      __builtin_amdgcn_s_setprio(1);
      #pragma unroll
      for (int n = 0; n < 3; ++n)
        #pragma unroll
        for (int m = 0; m < 4; ++m)
          acc[m][n] = MFMA16(aF[m], bB[n], acc[m][n]);
      __builtin_amdgcn_s_setprio(0);
    }
  }

  #pragma unroll
  for (int n = 0; n < 3; ++n) {
    const int col = c0 + wn * 48 + n * 16 + fr;
    const float bias = b_down[e * HDIM + col];
    #pragma unroll
    for (int m = 0; m < 4; ++m) {
      #pragma unroll
      for (int r = 0; r < 4; ++r) {
        int slot = m0 + wm * 64 + m * 16 + fq * 4 + r;
        if (slot < ce) {
          int token = tok[e * NTOK + slot];
          float w = wgt[e * NTOK + slot];
          atomicAdd(&out[(size_t)token * HDIM + col], w * (acc[m][n][r] + bias));
        }
      }
    }
  }
}

extern "C" void kernel_launch(void* const* d_in, const int* in_sizes, int n_in,
                              void* d_out, int out_size, void* d_ws,
                              size_t ws_size, hipStream_t stream) {
  const float* x = (const float*)d_in[0];
  const float* norm_w = (const float*)d_in[1];
  const float* gate_w = (const float*)d_in[2];
  const float* gate_b = (const float*)d_in[3];
  const float* w_gate_up = (const float*)d_in[4];
  const float* b_gate_up = (const float*)d_in[5];
  const float* w_down = (const float*)d_in[6];
  const float* b_down = (const float*)d_in[7];
  float* out = (float*)d_out;

  char* ws = (char*)d_ws;
  unsigned short* t_bf = (unsigned short*)ws;
  ws += (size_t)NTOK * HDIM * 2;
  unsigned short* act_bf = (unsigned short*)ws;
  ws += (size_t)NEXP * NTOK * IDIM * 2;
  int* cnt = (int*)ws;
  ws += 256;
  int* tok = (int*)ws;
  ws += (size_t)NEXP * NTOK * 4;
  float* wgt = (float*)ws;
  ws += (size_t)NEXP * NTOK * 4;

  hipMemsetAsync(cnt, 0, NEXP * sizeof(int), stream);
  init_out_k<<<2880, 256, 0, stream>>>(x, out);
  rms_router_k<<<NTOK, 256, 0, stream>>>(x, norm_w, gate_w, gate_b, t_bf, cnt,
                                         tok, wgt);
  // h = u*4 + z : the up-to-4 row-tile twins of each (expert, col-slice)
  // are CONSECUTIVE blocks -> co-resident -> weights fetched from HBM once.
  gemm1_k<<<360 * 4, 512, 0, stream>>>(t_bf, w_gate_up, b_gate_up, cnt, tok,
                                       act_bf);
  gemm2_k<<<240 * 4, 512, 0, stream>>>(act_bf, w_down, b_down, cnt, tok, wgt,
                                       out);
}